// Round 3
// baseline (41433.517 us; speedup 1.0000x reference)
//
#include <hip/hip_runtime.h>
#include <math.h>

#define BATCHN 32
#define SEQT   2048
#define NMELS  80
#define HIDN   512
#define NCLSN  64
#define BTROWS (BATCHN*SEQT)   // 65536
#define WUP    256
#define CHK    512

typedef _Float16 f16x2 __attribute__((ext_vector_type(2)));

#if defined(__has_builtin)
#if __has_builtin(__builtin_amdgcn_fdot2)
#define FDOT2(a,b,c) __builtin_amdgcn_fdot2((a),(b),(c),false)
#endif
#endif
#ifndef FDOT2
#define FDOT2(a,b,c) ((float)(a).x*(float)(b).x + (float)(a).y*(float)(b).y + (c))
#endif

__device__ inline unsigned pkf16(float a, float b){
  union { f16x2 h; unsigned u; } c;
  c.h.x = (_Float16)a; c.h.y = (_Float16)b;
  return c.u;
}
__device__ inline f16x2 uph(unsigned u){
  union { unsigned u; f16x2 h; } c; c.u = u; return c.h;
}
__device__ inline float wave_sum(float v) {
  #pragma unroll
  for (int o = 32; o > 0; o >>= 1) v += __shfl_xor(v, o, 64);
  return v;
}
__device__ inline float ftanh(float x) {
  float ax = fabsf(x);
  float e = __expf(2.0f*ax);
  float t = 1.0f - 2.0f/(e + 1.0f);
  return copysignf(t, x);
}
__device__ inline unsigned pack_bf16(float a, float b) {
  union { float f; unsigned u; } ua, ub; ua.f = a; ub.f = b;
  unsigned lo = (ua.u + 0x7fffu + ((ua.u >> 16) & 1u)) >> 16;
  unsigned hi = (ub.u + 0x7fffu + ((ub.u >> 16) & 1u)) & 0xffff0000u;
  return (lo & 0xffffu) | hi;
}
__device__ inline float bf_lo(unsigned p) { union { unsigned u; float f; } c; c.u = p << 16; return c.f; }
__device__ inline float bf_hi(unsigned p) { union { unsigned u; float f; } c; c.u = p & 0xffff0000u; return c.f; }

// ============================================================================
// MAIN PATH (ws >= ~68MB)
// ============================================================================

// ---- prep: per 32-row tile: xs0, be0, xs1, then be1 = (be0 @ B1^T)/xs1 (f16) ----
#define PBM 32
__global__ __launch_bounds__(256) void prep_kernel(
    const float* __restrict__ feats, const float* __restrict__ B0,
    const float* __restrict__ B1,
    _Float16* __restrict__ be1h, float* __restrict__ xs0w, float* __restrict__ xs1w)
{
  __shared__ float fts[PBM*80];            // 10KB
  __shared__ _Float16 be0h[PBM*520];       // 33.3KB (pad 520)
  __shared__ float rxs0_s[PBM], rxs1_s[PBM];
  __shared__ float Bs[16*521];             // 33.3KB
  const int tid = threadIdx.x;
  const size_t m0 = (size_t)blockIdx.x * PBM;

  for (int i = tid; i < PBM*80; i += 256) {
    int r = i/80, k = i - r*80;
    fts[i] = feats[(m0+r)*80 + k];
  }
  __syncthreads();
  {
    int r = tid >> 3, kc = tid & 7;
    float s = 0.f;
    for (int k = kc*10; k < kc*10+10; k++) { float v = fts[r*80+k]; s += v*v; }
    s += __shfl_xor(s,1,64); s += __shfl_xor(s,2,64); s += __shfl_xor(s,4,64);
    float xs0v = fmaxf(sqrtf(s), 1e-6f);
    if (kc == 0) { xs0w[m0+r] = xs0v; rxs0_s[r] = 1.0f/xs0v; }
  }
  __syncthreads();
  // be0: thread owns B0 rows tid, tid+256 (f16-packed regs)
  {
    unsigned b0a[40], b0b[40];
    #pragma unroll
    for (int i = 0; i < 40; i++) {
      float2 v = *(const float2*)(B0 + (size_t)tid*80 + 2*i);
      b0a[i] = pkf16(v.x, v.y);
      float2 w = *(const float2*)(B0 + (size_t)(tid+256)*80 + 2*i);
      b0b[i] = pkf16(w.x, w.y);
    }
    for (int r = 0; r < PBM; r++) {
      float rx = rxs0_s[r];
      float a0 = 0.f, a1 = 0.f;
      #pragma unroll
      for (int i = 0; i < 40; i++) {
        float2 f = *(const float2*)(fts + r*80 + 2*i);
        f16x2 fa; fa.x = (_Float16)(f.x*rx); fa.y = (_Float16)(f.y*rx);
        a0 = FDOT2(uph(b0a[i]), fa, a0);
        a1 = FDOT2(uph(b0b[i]), fa, a1);
      }
      be0h[r*520 + tid]     = (_Float16)a0;
      be0h[r*520 + tid+256] = (_Float16)a1;
    }
  }
  __syncthreads();
  {
    int r = tid >> 3, kc = tid & 7;
    float s = 0.f;
    for (int k = kc*64; k < kc*64+64; k++) { float v = (float)be0h[r*520+k]; s += v*v; }
    s += __shfl_xor(s,1,64); s += __shfl_xor(s,2,64); s += __shfl_xor(s,4,64);
    float xs1v = fmaxf(sqrtf(s), 1e-6f);
    if (kc == 0) { xs1w[m0+r] = xs1v; rxs1_s[r] = 1.0f/xs1v; }
  }
  __syncthreads();
  // GEMM: be1[r][n] = (sum_k be0[r][k]*B1[n][k]) * rxs1[r]
  const int tx = tid & 63, ty = tid >> 6;
  float acc[8][8] = {};
  for (int k0 = 0; k0 < 512; k0 += 16) {
    for (int nn = tid; nn < 512; nn += 256) {
      const float* src = B1 + (size_t)nn*512 + k0;
      #pragma unroll
      for (int q = 0; q < 4; q++) {
        float4 v = *(const float4*)(src + 4*q);
        Bs[(4*q+0)*521 + nn] = v.x; Bs[(4*q+1)*521 + nn] = v.y;
        Bs[(4*q+2)*521 + nn] = v.z; Bs[(4*q+3)*521 + nn] = v.w;
      }
    }
    __syncthreads();
    #pragma unroll
    for (int kk = 0; kk < 16; kk += 2) {
      float a0[8], a1[8];
      #pragma unroll
      for (int i = 0; i < 8; i++) {
        f16x2 p = *(const f16x2*)&be0h[(ty*8+i)*520 + k0 + kk];
        a0[i] = (float)p.x; a1[i] = (float)p.y;
      }
      float b0v[8], b1v[8];
      #pragma unroll
      for (int j = 0; j < 8; j++) {
        b0v[j] = Bs[kk*521 + tx*8+j];
        b1v[j] = Bs[(kk+1)*521 + tx*8+j];
      }
      #pragma unroll
      for (int i = 0; i < 8; i++)
        #pragma unroll
        for (int j = 0; j < 8; j++)
          acc[i][j] += a0[i]*b0v[j] + a1[i]*b1v[j];
    }
    __syncthreads();
  }
  #pragma unroll
  for (int i = 0; i < 8; i++) {
    int r = ty*8+i; float sc = rxs1_s[r];
    uint4 d;
    d.x = pkf16(acc[i][0]*sc, acc[i][1]*sc);
    d.y = pkf16(acc[i][2]*sc, acc[i][3]*sc);
    d.z = pkf16(acc[i][4]*sc, acc[i][5]*sc);
    d.w = pkf16(acc[i][6]*sc, acc[i][7]*sc);
    *(uint4*)(be1h + (m0+r)*512 + tx*8) = d;
  }
}

// ---- head base: out[m][c] = head_b[c] + sum_k be1[m][k]*whb[c][k] ----
__global__ __launch_bounds__(256) void headbase_kernel(
    const _Float16* __restrict__ A, const float* __restrict__ Bt,
    float* __restrict__ C, const float* __restrict__ bias)
{
  __shared__ float As[16][132];
  __shared__ float Bs[16][68];
  const int tid = threadIdx.x;
  const size_t m0 = (size_t)blockIdx.x * 128;
  const int tx = tid & 15, ty = tid >> 4;
  float acc[8][4] = {};
  for (int k0 = 0; k0 < 512; k0 += 16) {
    {
      int m = tid >> 1, kk2 = (tid*4) & 7;   // 4 dwords = 8 f16 per thread
      uint4 v = *(const uint4*)(A + (m0+m)*512 + k0 + kk2*2);
      f16x2 h0 = uph(v.x), h1 = uph(v.y), h2v = uph(v.z), h3 = uph(v.w);
      As[kk2*2+0][m] = (float)h0.x; As[kk2*2+1][m] = (float)h0.y;
      As[kk2*2+2][m] = (float)h1.x; As[kk2*2+3][m] = (float)h1.y;
      As[kk2*2+4][m] = (float)h2v.x; As[kk2*2+5][m] = (float)h2v.y;
      As[kk2*2+6][m] = (float)h3.x; As[kk2*2+7][m] = (float)h3.y;
    }
    {
      int n = tid >> 2, kq = tid & 3;
      float4 v = *(const float4*)(Bt + (size_t)n*1024 + k0 + kq*4);
      Bs[kq*4+0][n] = v.x; Bs[kq*4+1][n] = v.y;
      Bs[kq*4+2][n] = v.z; Bs[kq*4+3][n] = v.w;
    }
    __syncthreads();
    #pragma unroll
    for (int kk = 0; kk < 16; kk++) {
      float a[8], b[4];
      #pragma unroll
      for (int i = 0; i < 8; i++) a[i] = As[kk][ty*8+i];
      #pragma unroll
      for (int j = 0; j < 4; j++) b[j] = Bs[kk][tx*4+j];
      #pragma unroll
      for (int i = 0; i < 8; i++)
        #pragma unroll
        for (int j = 0; j < 4; j++) acc[i][j] += a[i]*b[j];
    }
    __syncthreads();
  }
  #pragma unroll
  for (int i = 0; i < 8; i++) {
    size_t m = m0 + ty*8 + i;
    float4 v;
    v.x = acc[i][0] + bias[tx*4+0];
    v.y = acc[i][1] + bias[tx*4+1];
    v.z = acc[i][2] + bias[tx*4+2];
    v.w = acc[i][3] + bias[tx*4+3];
    *(float4*)(C + m*64 + tx*4) = v;
  }
}

// ---- recurrence: 128 (batch,chunk) sequences x 2 WGs (A: C1/h, B: W1/head) ----
__global__ __launch_bounds__(512, 1) void recur2_kernel(
    const float* __restrict__ feats,
    const float* __restrict__ B0,
    const float* __restrict__ C1, const float* __restrict__ W1,
    const float* __restrict__ ltc,
    const float* __restrict__ tau0p, const float* __restrict__ gammap,
    const float* __restrict__ head_w,
    const _Float16* __restrict__ be1h,
    const float* __restrict__ xs0w, const float* __restrict__ xs1w,
    float* __restrict__ out,
    unsigned* __restrict__ PAY, unsigned* __restrict__ EEB,
    unsigned* __restrict__ FLG)
{
  const int n = blockIdx.x;
  const int q = n >> 4, r = n & 15;
  const bool isA = (r < 8);
  const int p = q*8 + (r & 7);     // A=16q+r', B=16q+r'+8 share blockIdx%8 (XCD heuristic)
  const int b = p & 31, chunk = p >> 5;
  const int t_out = chunk * CHK;
  const int t_begin = (chunk == 0) ? 0 : (t_out - WUP);
  const int D = t_out + CHK - t_begin;   // 512 or 768
  const int tid = threadIdx.x;
  const int lane = tid & 63;

  unsigned* payp  = PAY + (size_t)p*512;
  unsigned* eebp  = EEB + (size_t)p*256;
  unsigned* flagA = FLG + (size_t)p*64;
  unsigned* flagB = flagA + 32;

  struct AS {
    unsigned c1[64*512];     // C1 k in [384,512) packed pairs, [k2][row]  128KB
    _Float16 hmat[512];
    _Float16 ebuf[512];
    float xn[80];
    float fts[80];
    float red[8];
  };
  struct BS {
    unsigned w1[64*512];     // W1 k in [384,512)                          128KB
    _Float16 epk[512];
    _Float16 hpk[512];
    _Float16 eeb2[512];
    float orow[64];
  };
  __shared__ union { AS a; BS b; } sh;

  f16x2 wreg[192];   // k in [0,384) of this thread's row, f16 pairs

  if (isA) {
    {
      const float2* src = (const float2*)(C1 + (size_t)tid*512);
      #pragma unroll
      for (int i = 0; i < 192; i++) { float2 v = src[i]; wreg[i] = uph(pkf16(v.x, v.y)); }
      #pragma unroll
      for (int i = 0; i < 64; i++) { float2 v = src[192+i]; sh.a.c1[i*512+tid] = pkf16(v.x, v.y); }
    }
    float ltcv = ltc[tid];
    float spl = (ltcv > 20.f) ? ltcv : log1pf(__expf(ltcv));
    const float a0 = 0.1f / (1.0f + spl);
    const float tau0v = *tau0p, gmv = *gammap;
    float h = 0.f;
    sh.a.hmat[tid] = (_Float16)0.f;
    __syncthreads();

    for (int i = 0; i <= D; ++i) {
      const int gt = t_begin + i;
      const bool real = (i < D);
      const size_t bt = (size_t)b*SEQT + (real ? gt : gt-1);
      float xs1v = 1.f;
      if (real) {
        if (tid < 80) sh.a.fts[tid] = feats[bt*80 + tid];
        xs1v = xs1w[bt];
      }
      __syncthreads();                   // fts ready; prev hmat writes done
      if (real && tid < 80) {
        float rx = 1.0f / xs0w[bt];
        sh.a.xn[tid] = sh.a.fts[tid] * rx;
      }
      __syncthreads();
      if (real) {
        // u = C1[tid,:] . h
        float u = 0.f;
        const f16x2* hp = (const f16x2*)sh.a.hmat;
        #pragma unroll
        for (int k = 0; k < 192; k++) u = FDOT2(wreg[k], hp[k], u);
        #pragma unroll
        for (int k = 0; k < 64; k++) u = FDOT2(uph(sh.a.c1[k*512+tid]), hp[192+k], u);
        float g = ftanh(u);
        // be0 = B0[tid,:] . xn  (B0 row streamed from L2, off 80KB LDS budget)
        float be0 = 0.f;
        const float* b0r = B0 + (size_t)tid*80;
        #pragma unroll
        for (int k4 = 0; k4 < 20; k4++) {
          float4 w = *(const float4*)(b0r + 4*k4);
          float4 x = *(const float4*)(sh.a.xn + 4*k4);
          be0 += w.x*x.x + w.y*x.y + w.z*x.z + w.w*x.w;
        }
        float e = be0 - xs1v * g;
        sh.a.ebuf[tid] = (_Float16)e;
        float es = wave_sum(e*e);
        if (lane == 0) sh.a.red[tid >> 6] = es;
      }
      __syncthreads();                   // ebuf/red ready; hmat reads done
      {
        unsigned v = (tid < 256) ? ((const unsigned*)sh.a.ebuf)[tid]
                                 : ((const unsigned*)sh.a.hmat)[tid-256];
        __hip_atomic_store(&payp[tid], v, __ATOMIC_RELAXED, __HIP_MEMORY_SCOPE_AGENT);
      }
      __syncthreads();                   // drain stores before flag
      if (tid == 0)
        __hip_atomic_fetch_add(flagA, 1u, __ATOMIC_RELEASE, __HIP_MEMORY_SCOPE_AGENT);
      if (!real) break;
      float tot = sh.a.red[0]+sh.a.red[1]+sh.a.red[2]+sh.a.red[3]
                + sh.a.red[4]+sh.a.red[5]+sh.a.red[6]+sh.a.red[7];
      float rel = fminf(sqrtf(tot)/xs1v, 4.0f);
      float sp = 1.0f/(1.0f + __expf(-(rel - tau0v)/gmv));
      float be1v = (float)be1h[bt*512 + tid];
      if (tid == 0) {
        unsigned tgt = (unsigned)(i+1);
        while (__hip_atomic_load(flagB, __ATOMIC_ACQUIRE, __HIP_MEMORY_SCOPE_AGENT) < tgt) {}
      }
      __syncthreads();
      unsigned ed = __hip_atomic_load(&eebp[tid>>1], __ATOMIC_RELAXED, __HIP_MEMORY_SCOPE_AGENT);
      f16x2 ep = uph(ed);
      float eev = (tid & 1) ? (float)ep.y : (float)ep.x;
      float ih = 0.2f*h + 0.6f*be1v + 0.2f*sp*eev;
      float th = ftanh(ih);
      h = h + a0*(1.0f + sp)*(th - h);
      sh.a.hmat[tid] = (_Float16)h;
    }
  } else {
    {
      const float2* src = (const float2*)(W1 + (size_t)tid*512);
      #pragma unroll
      for (int i = 0; i < 192; i++) { float2 v = src[i]; wreg[i] = uph(pkf16(v.x, v.y)); }
      #pragma unroll
      for (int i = 0; i < 64; i++) { float2 v = src[192+i]; sh.b.w1[i*512+tid] = pkf16(v.x, v.y); }
    }
    __syncthreads();
    const int cc = tid >> 3, jc = tid & 7;
    for (int i = 0; i <= D; ++i) {
      if (tid == 0) {
        unsigned tgt = (unsigned)(i+1);
        while (__hip_atomic_load(flagA, __ATOMIC_ACQUIRE, __HIP_MEMORY_SCOPE_AGENT) < tgt) {}
      }
      __syncthreads();
      {
        unsigned v = __hip_atomic_load(&payp[tid], __ATOMIC_RELAXED, __HIP_MEMORY_SCOPE_AGENT);
        if (tid < 256) ((unsigned*)sh.b.epk)[tid] = v;
        else           ((unsigned*)sh.b.hpk)[tid-256] = v;
      }
      __syncthreads();
      if (i < D) {
        float ee = 0.f;
        const f16x2* ep2 = (const f16x2*)sh.b.epk;
        #pragma unroll
        for (int k = 0; k < 192; k++) ee = FDOT2(wreg[k], ep2[k], ee);
        #pragma unroll
        for (int k = 0; k < 64; k++) ee = FDOT2(uph(sh.b.w1[k*512+tid]), ep2[192+k], ee);
        sh.b.eeb2[tid] = (_Float16)ee;
        __syncthreads();
        if (tid < 256)
          __hip_atomic_store(&eebp[tid], ((const unsigned*)sh.b.eeb2)[tid],
                             __ATOMIC_RELAXED, __HIP_MEMORY_SCOPE_AGENT);
        __syncthreads();
        if (tid == 0)
          __hip_atomic_fetch_add(flagB, 1u, __ATOMIC_RELEASE, __HIP_MEMORY_SCOPE_AGENT);
      }
      // deferred head for out row R (uses h at entry of step i), off critical path
      const int R = t_begin + i - 1;
      if (R >= t_out) {
        const f16x2* hp2 = (const f16x2*)sh.b.hpk;
        float ha = 0.f;
        #pragma unroll
        for (int k = 0; k < 32; k++) {
          int j2 = jc*32 + k;
          float2 w = *(const float2*)(head_w + (size_t)cc*1024 + 2*j2);  // L2-resident
          f16x2 hv = hp2[j2];
          ha += w.x*(float)hv.x + w.y*(float)hv.y;
        }
        ha += __shfl_xor(ha,1,64); ha += __shfl_xor(ha,2,64); ha += __shfl_xor(ha,4,64);
        if (jc == 0) sh.b.orow[cc] = ha;
        __syncthreads();
        if (tid < 64) {
          size_t o = ((size_t)b*SEQT + R)*64 + tid;
          out[o] = out[o] + sh.b.orow[tid];
        }
      }
      __syncthreads();
    }
  }
}

// ============================================================================
// FALLBACK PATH (round-2, known-good, ~2.8MB ws) — used when ws is small
// ============================================================================

__global__ __launch_bounds__(256) void rownorm_kernel(
    const float* __restrict__ X, float* __restrict__ xs, int M, int K)
{
  int wave = threadIdx.x >> 6, lane = threadIdx.x & 63;
  int m = blockIdx.x*4 + wave;
  if (m >= M) return;
  const float* row = X + (size_t)m*K;
  float acc = 0.f;
  for (int k = lane; k < K; k += 64) { float v = row[k]; acc += v*v; }
  acc = wave_sum(acc);
  if (lane == 0) xs[m] = fmaxf(sqrtf(acc), 1e-6f);
}

__global__ __launch_bounds__(256) void initout_kernel(
    float* __restrict__ out, const float* __restrict__ head_b)
{
  int i4 = blockIdx.x*256 + threadIdx.x;
  float4 v = ((const float4*)head_b)[i4 & 15];
  ((float4*)out)[i4] = v;
}

__global__ __launch_bounds__(256, 1) void recur_kernel(
    const float* __restrict__ feats,
    const float* __restrict__ B0,
    const float* __restrict__ C1, const float* __restrict__ B1,
    const float* __restrict__ W1,
    const float* __restrict__ ltc,
    const float* __restrict__ tau0p, const float* __restrict__ gammap,
    const float* __restrict__ head_w,
    const float* __restrict__ xs0v,
    float* __restrict__ out,
    float* __restrict__ PG, float* __restrict__ PB,
    float* __restrict__ BE, float* __restrict__ PS,
    unsigned int* __restrict__ cnt)
{
  const int wg = blockIdx.x;
  const int x = wg & 7, s = (wg >> 3) & 7, qq = wg >> 6;
  const int b = x*4 + qq;
  const int row0 = s*64;
  const int tid = threadIdx.x;
  const int r = tid >> 2, kc = tid & 3;
  const int wid = tid >> 6, lane = tid & 63;

  __shared__ float b0_s[64*84];
  __shared__ float whh_s[64*68];
  __shared__ float whb_s[64*68];
  __shared__ float er_s[512];
  __shared__ float ft_s[80];
  __shared__ float h_s[64];
  __shared__ float bo_s[64];
  __shared__ float bv_s[64];
  __shared__ float a0_s[64];
  __shared__ float red_s[4], red2_s[4];

  float c1c[128];
  unsigned b1p[64];
  float w1r[128];
  #pragma unroll
  for (int j = 0; j < 2; j++) {
    const float* src = C1 + (size_t)(tid + j*256)*512 + row0;
    #pragma unroll
    for (int k4 = 0; k4 < 16; k4++) {
      float4 v = *(const float4*)(src + 4*k4);
      c1c[j*64+4*k4]=v.x; c1c[j*64+4*k4+1]=v.y; c1c[j*64+4*k4+2]=v.z; c1c[j*64+4*k4+3]=v.w;
    }
  }
  #pragma unroll
  for (int j = 0; j < 2; j++) {
    const float* src = B1 + (size_t)(tid + j*256)*512 + row0;
    #pragma unroll
    for (int k4 = 0; k4 < 16; k4++) {
      float4 v = *(const float4*)(src + 4*k4);
      b1p[j*32+2*k4]   = pack_bf16(v.x, v.y);
      b1p[j*32+2*k4+1] = pack_bf16(v.z, v.w);
    }
  }
  {
    const float* src = W1 + (size_t)(row0 + r)*512;
    #pragma unroll
    for (int j4 = 0; j4 < 32; j4++) {
      const int f = kc*32 + ((j4 + kc) & 31);
      float4 v = *(const float4*)(src + 4*f);
      w1r[4*j4]=v.x; w1r[4*j4+1]=v.y; w1r[4*j4+2]=v.z; w1r[4*j4+3]=v.w;
    }
  }
  for (int i = tid; i < 5120; i += 256) {
    int rr = i/80, kk = i - rr*80;
    b0_s[rr*84 + kk] = B0[(size_t)(row0+rr)*80 + kk];
  }
  for (int i = tid; i < 4096; i += 256) {
    int c = i >> 6, j = i & 63;
    whh_s[c*68+j] = head_w[(size_t)c*1024 + row0 + j];
    whb_s[c*68+j] = head_w[(size_t)c*1024 + 512 + row0 + j];
  }
  if (tid < 64) {
    float xv = ltc[row0 + tid];
    float spl = (xv > 20.f) ? xv : log1pf(__expf(xv));
    a0_s[tid] = 0.1f / (1.0f + spl);
    h_s[tid] = 0.f;
  }
  const float tau0v = *tau0p, gmv = *gammap;
  unsigned int* cb = cnt + b*32;
  __syncthreads();

  for (int t = 0; t < SEQT; ++t) {
    const int par = t & 1;
    float* PGw = PG + (((size_t)par*BATCHN + b)*8 + s)*512;
    float* PBw = PB + (((size_t)par*BATCHN + b)*8 + s)*512;
    float* BEb = BE + ((size_t)par*BATCHN + b)*512;
    float* PSb = PS + ((size_t)par*BATCHN + b)*8;
    const size_t bt = (size_t)b*SEQT + t;

    if (tid < 80) ft_s[tid] = feats[bt*80 + tid];
    const float rxs0 = 1.0f / xs0v[bt];
    __syncthreads();

    float a = 0.f;
    #pragma unroll
    for (int j4 = 0; j4 < 5; j4++) {
      float4 bw = *(const float4*)(b0_s + r*84 + kc*20 + 4*j4);
      float4 fv = *(const float4*)(ft_s + kc*20 + 4*j4);
      a += bw.x*fv.x + bw.y*fv.y + bw.z*fv.z + bw.w*fv.w;
    }
    a += __shfl_xor(a, 1, 64); a += __shfl_xor(a, 2, 64);
    const float be0v = a * rxs0;
    if (kc == 0) {
      bo_s[r] = be0v;
      __hip_atomic_store(&BEb[row0 + r], be0v, __ATOMIC_RELAXED, __HIP_MEMORY_SCOPE_AGENT);
    }
    float sq = 0.25f*be0v*be0v;
    sq = wave_sum(sq);
    if (lane == 0) red_s[wid] = sq;
    __syncthreads();

    float pg0=0.f, pg1=0.f, pb0=0.f, pb1=0.f;
    #pragma unroll
    for (int k4 = 0; k4 < 16; k4++) {
      float4 hv = *(const float4*)(h_s + 4*k4);
      float4 ov = *(const float4*)(bo_s + 4*k4);
      pg0 += c1c[4*k4]*hv.x + c1c[4*k4+1]*hv.y + c1c[4*k4+2]*hv.z + c1c[4*k4+3]*hv.w;
      pg1 += c1c[64+4*k4]*hv.x + c1c[64+4*k4+1]*hv.y + c1c[64+4*k4+2]*hv.z + c1c[64+4*k4+3]*hv.w;
      unsigned p0 = b1p[2*k4], p1 = b1p[2*k4+1];
      unsigned q0 = b1p[32+2*k4], q1 = b1p[32+2*k4+1];
      pb0 += bf_lo(p0)*ov.x + bf_hi(p0)*ov.y + bf_lo(p1)*ov.z + bf_hi(p1)*ov.w;
      pb1 += bf_lo(q0)*ov.x + bf_hi(q0)*ov.y + bf_lo(q1)*ov.z + bf_hi(q1)*ov.w;
    }
    __hip_atomic_store(&PGw[tid],     pg0, __ATOMIC_RELAXED, __HIP_MEMORY_SCOPE_AGENT);
    __hip_atomic_store(&PGw[tid+256], pg1, __ATOMIC_RELAXED, __HIP_MEMORY_SCOPE_AGENT);
    __hip_atomic_store(&PBw[tid],     pb0, __ATOMIC_RELAXED, __HIP_MEMORY_SCOPE_AGENT);
    __hip_atomic_store(&PBw[tid+256], pb1, __ATOMIC_RELAXED, __HIP_MEMORY_SCOPE_AGENT);
    __syncthreads();

    if (tid == 0) {
      float ps = red_s[0]+red_s[1]+red_s[2]+red_s[3];
      __hip_atomic_store(&PSb[s], ps, __ATOMIC_RELAXED, __HIP_MEMORY_SCOPE_AGENT);
      __hip_atomic_fetch_add(cb, 1u, __ATOMIC_RELEASE, __HIP_MEMORY_SCOPE_AGENT);
      const unsigned tgt = 8u*(unsigned)(t+1);
      while (__hip_atomic_load(cb, __ATOMIC_ACQUIRE, __HIP_MEMORY_SCOPE_AGENT) < tgt)
        __builtin_amdgcn_s_sleep(1);
    }
    __syncthreads();

    const float* PGr = PG + ((size_t)par*BATCHN + b)*8*512;
    const float* PBr = PB + ((size_t)par*BATCHN + b)*8*512;
    float xsq = 0.f;
    #pragma unroll
    for (int s2 = 0; s2 < 8; s2++)
      xsq += __hip_atomic_load(&PSb[s2], __ATOMIC_RELAXED, __HIP_MEMORY_SCOPE_AGENT);
    const float xs1 = fmaxf(sqrtf(xsq), 1e-6f);
    const float rxs1 = 1.0f / xs1;

    float gp0=0.f, gp1=0.f;
    #pragma unroll
    for (int s2 = 0; s2 < 8; s2++) {
      gp0 += __hip_atomic_load(&PGr[s2*512 + tid],     __ATOMIC_RELAXED, __HIP_MEMORY_SCOPE_AGENT);
      gp1 += __hip_atomic_load(&PGr[s2*512 + tid+256], __ATOMIC_RELAXED, __HIP_MEMORY_SCOPE_AGENT);
    }
    const float bea = __hip_atomic_load(&BEb[tid],     __ATOMIC_RELAXED, __HIP_MEMORY_SCOPE_AGENT);
    const float beb = __hip_atomic_load(&BEb[tid+256], __ATOMIC_RELAXED, __HIP_MEMORY_SCOPE_AGENT);
    const float e0 = bea - xs1*ftanh(gp0);
    const float e1 = beb - xs1*ftanh(gp1);
    er_s[tid] = e0; er_s[tid+256] = e1;
    float es = wave_sum(e0*e0 + e1*e1);
    if (lane == 0) red2_s[wid] = es;

    float pbv = __hip_atomic_load(&PBr[(2*kc)*512   + row0 + r], __ATOMIC_RELAXED, __HIP_MEMORY_SCOPE_AGENT)
              + __hip_atomic_load(&PBr[(2*kc+1)*512 + row0 + r], __ATOMIC_RELAXED, __HIP_MEMORY_SCOPE_AGENT);
    pbv += __shfl_xor(pbv, 1, 64); pbv += __shfl_xor(pbv, 2, 64);
    const float be1v = pbv * rxs1;
    if (kc == 0) bv_s[r] = be1v;
    __syncthreads();

    const float rel = fminf(sqrtf(red2_s[0]+red2_s[1]+red2_s[2]+red2_s[3]) * rxs1, 4.0f);
    const float sp = 1.0f/(1.0f + __expf(-(rel - tau0v)/gmv));

    float ee = 0.f;
    #pragma unroll
    for (int j4 = 0; j4 < 32; j4++) {
      const int f = kc*32 + ((j4 + kc) & 31);
      float4 ev = *(const float4*)(er_s + 4*f);
      ee += w1r[4*j4]*ev.x + w1r[4*j4+1]*ev.y + w1r[4*j4+2]*ev.z + w1r[4*j4+3]*ev.w;
    }
    ee += __shfl_xor(ee, 1, 64); ee += __shfl_xor(ee, 2, 64);

    const float hold = h_s[r];
    const float ih = 0.2f*hold + 0.6f*be1v + 0.2f*sp*ee;
    const float th = ftanh(ih);
    const float hn = hold + a0_s[r]*(1.0f + sp)*(th - hold);
    if (kc == 0) h_s[r] = hn;
    __syncthreads();

    {
      const int c = r; const int j0 = kc*16;
      float hacc = 0.f;
      #pragma unroll
      for (int j4 = 0; j4 < 4; j4++) {
        float4 hv4 = *(const float4*)(h_s  + j0 + 4*j4);
        float4 bv4 = *(const float4*)(bv_s + j0 + 4*j4);
        float4 wh  = *(const float4*)(whh_s + c*68 + j0 + 4*j4);
        float4 wb  = *(const float4*)(whb_s + c*68 + j0 + 4*j4);
        hacc += hv4.x*wh.x + hv4.y*wh.y + hv4.z*wh.z + hv4.w*wh.w
              + bv4.x*wb.x + bv4.y*wb.y + bv4.z*wb.z + bv4.w*wb.w;
      }
      hacc += __shfl_xor(hacc, 1, 64); hacc += __shfl_xor(hacc, 2, 64);
      if (kc == 0) atomicAdd(&out[bt*64 + c], hacc);
    }
  }
}

// ============================================================================

extern "C" void kernel_launch(void* const* d_in, const int* in_sizes, int n_in,
                              void* d_out, int out_size, void* d_ws, size_t ws_size,
                              hipStream_t stream)
{
  (void)in_sizes; (void)n_in; (void)out_size;
  const float* feats  = (const float*)d_in[0];
  const float* B0     = (const float*)d_in[2];
  const float* C1     = (const float*)d_in[7];
  const float* B1     = (const float*)d_in[8];
  const float* W1     = (const float*)d_in[9];
  const float* tau0_1 = (const float*)d_in[10];
  const float* gamma1 = (const float*)d_in[11];
  const float* ltc1   = (const float*)d_in[12];
  const float* head_w = (const float*)d_in[13];
  const float* head_b = (const float*)d_in[14];
  float* out = (float*)d_out;

  // ---- main-path ws layout ----
  _Float16* be1h = (_Float16*)d_ws;                       // 64MB
  float* xs0w = (float*)(be1h + (size_t)BTROWS*HIDN);     // 256KB
  float* xs1w = xs0w + BTROWS;                            // 256KB
  unsigned* PAY = (unsigned*)(xs1w + BTROWS);             // 256KB
  unsigned* EEB = PAY + 128*512;                          // 128KB
  unsigned* FLG = EEB + 128*256;                          // 32KB
  size_t needed_main = (size_t)((char*)(FLG + 128*64) - (char*)d_ws);

  if (ws_size >= needed_main) {
    prep_kernel<<<BTROWS/PBM, 256, 0, stream>>>(feats, B0, B1, be1h, xs0w, xs1w);
    headbase_kernel<<<BTROWS/128, 256, 0, stream>>>(be1h, head_w + 512, out, head_b);
    hipMemsetAsync(FLG, 0, 128*64*sizeof(unsigned), stream);
    void* args[] = { (void*)&feats, (void*)&B0, (void*)&C1, (void*)&W1,
                     (void*)&ltc1, (void*)&tau0_1, (void*)&gamma1, (void*)&head_w,
                     (void*)&be1h, (void*)&xs0w, (void*)&xs1w, (void*)&out,
                     (void*)&PAY, (void*)&EEB, (void*)&FLG };
    hipError_t e = hipLaunchCooperativeKernel((void*)recur2_kernel, dim3(256), dim3(512),
                                              args, 0, stream);
    if (e != hipSuccess) {
      recur2_kernel<<<256, 512, 0, stream>>>(feats, B0, C1, W1, ltc1, tau0_1, gamma1,
                                             head_w, be1h, xs0w, xs1w, out, PAY, EEB, FLG);
    }
    return;
  }

  // ---- fallback (round-2, ~2.8MB) ----
  float* PG  = (float*)d_ws;
  float* PB  = PG + (size_t)2*BATCHN*8*HIDN;
  float* BE  = PB + (size_t)2*BATCHN*8*HIDN;
  float* PS  = BE + (size_t)2*BATCHN*HIDN;
  float* xs0 = PS + (size_t)2*BATCHN*8;
  unsigned int* cnt = (unsigned int*)(xs0 + BTROWS);
  size_t needed_fb = (size_t)((char*)(cnt + BATCHN*32) - (char*)d_ws);
  if (ws_size < needed_fb) return;

  rownorm_kernel<<<BTROWS/4, 256, 0, stream>>>(feats, xs0, BTROWS, NMELS);
  initout_kernel<<<(BTROWS*NCLSN/4)/256, 256, 0, stream>>>(out, head_b);
  hipMemsetAsync(cnt, 0, BATCHN*32*sizeof(unsigned int), stream);
  void* args[] = { (void*)&feats, (void*)&B0, (void*)&C1, (void*)&B1, (void*)&W1,
                   (void*)&ltc1, (void*)&tau0_1, (void*)&gamma1, (void*)&head_w,
                   (void*)&xs0, (void*)&out,
                   (void*)&PG, (void*)&PB, (void*)&BE, (void*)&PS, (void*)&cnt };
  hipError_t e = hipLaunchCooperativeKernel((void*)recur_kernel, dim3(256), dim3(256),
                                            args, 0, stream);
  if (e != hipSuccess) {
    recur_kernel<<<256, 256, 0, stream>>>(feats, B0, C1, B1, W1, ltc1, tau0_1, gamma1,
                                          head_w, xs0, out, PG, PB, BE, PS, cnt);
  }
}